// Round 11
// baseline (2165.905 us; speedup 1.0000x reference)
//
#include <hip/hip_runtime.h>
#include <hip/hip_bf16.h>
#include <cstdint>

#define RST 16777216  // 4096*4096 floats per rating class
typedef unsigned short u16;
typedef unsigned char u8;
typedef __attribute__((ext_vector_type(8))) short short8v;   // 8 bf16 in 4 VGPRs
typedef __attribute__((ext_vector_type(4))) float f32x4;

// MEASUREMENT ROUND: REP-looped kernels to surface per-kernel counters in top-5.
#define REP_LABELS 10
#define REP_TRSUP  32
#define REP_AGG    16
#define REP_LOGITS 20

__device__ __forceinline__ u16 f2bf(float x){
  unsigned int b = __float_as_uint(x);
  unsigned int r = (b + 0x7FFFu + ((b >> 16) & 1u)) >> 16;
  return (u16)r;
}
__device__ __forceinline__ float bf2f(u16 h){
  return __uint_as_float(((unsigned int)h) << 16);
}

// ---------------------------------------------------------------------------
// K1: label extraction + di row-counts.  (REP'd; no __restrict__ on outputs)
// ---------------------------------------------------------------------------
__global__ __launch_bounds__(256) void k_labels(const int* u, const int* v,
                                                const float* ratings, u8* L,
                                                int* di){
  __shared__ float row[4096];
  __shared__ int wsum[4];
  int i = blockIdx.x;
  int tid = threadIdx.x;
  int lane = tid & 63, wid = tid >> 6;
  int U = u[i];
  int j0 = tid * 8;
  int vj[8];
#pragma unroll
  for (int k = 0; k < 8; k++) vj[k] = v[j0 + k];
  const float* rbase = ratings + (size_t)U * 4096;
  for (int rep = 0; rep < REP_LABELS; rep++){
    int lab[8];
#pragma unroll
    for (int k = 0; k < 8; k++) lab[k] = 5;
    for (int c = 0; c < 5; c++){
      const float4* src = (const float4*)(rbase + (size_t)c * RST);
#pragma unroll
      for (int k = 0; k < 4; k++) ((float4*)row)[tid + k*256] = src[tid + k*256];
      __syncthreads();
#pragma unroll
      for (int k = 0; k < 8; k++) if (row[vj[k]] > 0.5f) lab[k] = c;
      __syncthreads();
    }
    unsigned int lo = 0, hi = 0;
    int cnt = 0;
#pragma unroll
    for (int k = 0; k < 4; k++){
      lo |= ((unsigned)lab[k]) << (8*k); hi |= ((unsigned)lab[k+4]) << (8*k);
      cnt += (lab[k] != 5); cnt += (lab[k+4] != 5);
    }
    *(uint2*)(L + (size_t)i * 2048 + j0) = make_uint2(lo, hi);
#pragma unroll
    for (int o = 32; o > 0; o >>= 1) cnt += __shfl_down(cnt, o);
    if (lane == 0) wsum[wid] = cnt;
    __syncthreads();
    if (tid == 0) di[i] = wsum[0] + wsum[1] + wsum[2] + wsum[3];
    __syncthreads();
  }
}

// ---------------------------------------------------------------------------
// K2: fused transpose + support.  (REP'd)
// ---------------------------------------------------------------------------
__global__ __launch_bounds__(256) void k_trsup(const u8* L, u8* LT,
    const int* u, const int* v,
    const float* u_emb, const float* v_emb, const float* gc_w,
    float* S){
  __shared__ u8 tile[64][64];
  int tid = threadIdx.x;
  for (int rep = 0; rep < REP_TRSUP; rep++){
    if (blockIdx.x < 1024){
      int jb = blockIdx.x & 31, ib = blockIdx.x >> 5;
      int i0 = ib * 64, j0 = jb * 64;
      int r = tid >> 2, cq = tid & 3;
      uint4 d = *(const uint4*)(L + (size_t)(i0 + r) * 2048 + j0 + cq * 16);
      *(uint4*)&tile[r][cq * 16] = d;
      __syncthreads();
      u8 ob[16];
#pragma unroll
      for (int k = 0; k < 16; k++) ob[k] = tile[cq * 16 + k][r];
      *(uint4*)(LT + (size_t)(j0 + r) * 2048 + i0 + cq * 16) = *(uint4*)ob;
      __syncthreads();
    } else {
      int b = blockIdx.x - 1024;
      int c = b >> 6, nblk = b & 63;
      int lane = tid & 63, wid = tid >> 6;
      int n0 = nblk * 64 + wid * 16;
      float w[64];
#pragma unroll
      for (int d = 0; d < 64; d++) w[d] = gc_w[c * 4096 + d * 64 + lane];
      for (int k = 0; k < 16; k++){
        int n = n0 + k;
        int idx = (n < 2048) ? u[n] : v[n - 2048];
        const float* xr = (n < 2048) ? (u_emb + (size_t)idx * 64) : (v_emb + (size_t)idx * 64);
        float xv = xr[lane];
        float acc = 0.f;
#pragma unroll
        for (int d = 0; d < 64; d++) acc += __shfl(xv, d) * w[d];
        S[((size_t)c * 4096 + n) * 64 + lane] = acc;
      }
    }
  }
}

// ---------------------------------------------------------------------------
// K3: sparse aggregate, in-block compaction.  (REP'd)
// ---------------------------------------------------------------------------
__global__ __launch_bounds__(256) void k_agg(const u8* L, const u8* LT,
    const float* S, float* aggsum, int* du){
  __shared__ u16 lst[2048];
  __shared__ int wbase[4];
  __shared__ float red[4][64];
  int r = blockIdx.x;
  int tid = threadIdx.x;
  int lane = tid & 63, wid = tid >> 6;
  bool uside = (r < 2048);
  const u8* rowp = uside ? (L + (size_t)r * 2048) : (LT + (size_t)(r - 2048) * 2048);
  for (int rep = 0; rep < REP_AGG; rep++){
    uint2 d = ((const uint2*)rowp)[tid];
    int lab[8];
#pragma unroll
    for (int k = 0; k < 4; k++){ lab[k] = (d.x >> (8*k)) & 255; lab[k+4] = (d.y >> (8*k)) & 255; }
    int cnt = 0;
#pragma unroll
    for (int k = 0; k < 8; k++) cnt += (lab[k] != 5);
    int pre = cnt;
#pragma unroll
    for (int o = 1; o < 64; o <<= 1){ int t = __shfl_up(pre, o); if (lane >= o) pre += t; }
    if (lane == 63) wbase[wid] = pre;
    __syncthreads();
    int base = 0;
#pragma unroll
    for (int w = 0; w < 4; w++) base += (w < wid) ? wbase[w] : 0;
    int total = wbase[0] + wbase[1] + wbase[2] + wbase[3];
    int off = base + (pre - cnt);
    int j0 = tid * 8;
#pragma unroll
    for (int k = 0; k < 8; k++)
      if (lab[k] != 5) lst[off++] = (u16)(((j0 + k) << 3) | lab[k]);
    if (!uside && tid == 0) du[r - 2048] = total;
    __syncthreads();
    const float* Sop = S + (uside ? 131072 : 0) + lane;
    int e0 = (wid * total) >> 2, e1 = ((wid + 1) * total) >> 2;
    float a0 = 0.f, a1 = 0.f, a2 = 0.f, a3 = 0.f;
    int e = e0;
    for (; e + 4 <= e1; e += 4){
      int x0 = lst[e], x1 = lst[e+1], x2 = lst[e+2], x3 = lst[e+3];
      a0 += Sop[(size_t)(x0 & 7) * 262144 + (size_t)(x0 >> 3) * 64];
      a1 += Sop[(size_t)(x1 & 7) * 262144 + (size_t)(x1 >> 3) * 64];
      a2 += Sop[(size_t)(x2 & 7) * 262144 + (size_t)(x2 >> 3) * 64];
      a3 += Sop[(size_t)(x3 & 7) * 262144 + (size_t)(x3 >> 3) * 64];
    }
    for (; e < e1; e++){
      int x = lst[e];
      a0 += Sop[(size_t)(x & 7) * 262144 + (size_t)(x >> 3) * 64];
    }
    red[wid][lane] = (a0 + a1) + (a2 + a3);
    __syncthreads();
    if (wid == 0) aggsum[(size_t)r * 64 + lane] = red[0][lane] + red[1][lane] + red[2][lane] + red[3][lane];
    __syncthreads();
  }
}

// ---------------------------------------------------------------------------
// K4: hidden (r7 form, unchanged, REP=1)
// ---------------------------------------------------------------------------
__global__ __launch_bounds__(256) void k_hidden(const float* __restrict__ aggsum, const int* __restrict__ du, const int* __restrict__ di,
    const float* __restrict__ gc_b, const float* __restrict__ dense_w, const float* __restrict__ dense_b,
    float* __restrict__ hidden){
  int wid = threadIdx.x >> 6, lane = threadIdx.x & 63;
  int r = blockIdx.x * 4 + wid;
  float a = aggsum[(size_t)r * 64 + lane];
  int cnt = (r < 2048) ? du[r] : di[r - 2048];
  float inv = (cnt > 0) ? (1.0f / (float)cnt) : 0.0f;
  float bsum = 0.f;
#pragma unroll
  for (int c = 0; c < 5; c++) bsum += gc_b[c * 64 + lane];
  float z = fmaxf(a * inv + bsum, 0.f);
  __shared__ float zb[4][64];
  zb[wid][lane] = z;
  __syncthreads();
  if (lane < 32){
    float s = dense_b[lane];
#pragma unroll
    for (int h = 0; h < 64; h++) s += zb[wid][h] * dense_w[h * 32 + lane];
    hidden[(size_t)r * 32 + lane] = 1.0f / (1.0f + __expf(-s));
  }
}

// ---------------------------------------------------------------------------
// K5: MFMA logits (REP'd)
// ---------------------------------------------------------------------------
#define EPI(l, lab, outp) do{ \
  float mx = fmaxf(fmaxf(fmaxf(l[0], l[1]), fmaxf(l[2], l[3])), l[4]); \
  float e0 = __expf(l[0]-mx), e1 = __expf(l[1]-mx), e2 = __expf(l[2]-mx), e3 = __expf(l[3]-mx), e4 = __expf(l[4]-mx); \
  float ssum = e0 + e1 + e2 + e3 + e4; \
  *(outp) = (e1 + 2.f*e2 + 3.f*e3 + 4.f*e4) / ssum; \
  if ((lab) < 5){ \
    int pred = 0; float bm = l[0]; \
    if (l[1] > bm){ bm = l[1]; pred = 1; } \
    if (l[2] > bm){ bm = l[2]; pred = 2; } \
    if (l[3] > bm){ bm = l[3]; pred = 3; } \
    if (l[4] > bm){ bm = l[4]; pred = 4; } \
    float ll = (lab)==0 ? l[0] : ((lab)==1 ? l[1] : ((lab)==2 ? l[2] : ((lab)==3 ? l[3] : l[4]))); \
    lsum += __logf(ssum) + mx - ll; \
    acnt += (pred == (lab)); \
  } \
}while(0)

__global__ __launch_bounds__(256) void k_logits(const float* hidden, const float* dec_w,
    const u8* L, float* mhat, float* lpart, int* apart){
  __shared__ float hu_s[512];          // 16 x 32
  __shared__ float tsf[5 * 16 * 36];   // padded stride 36
  __shared__ float wl[4]; __shared__ int wa[4];
  int tid = threadIdx.x;
  int lane = tid & 63, w = tid >> 6;
  int i0 = blockIdx.y * 16;
  for (int rep = 0; rep < REP_LOGITS; rep++){
    if (tid < 128) ((float4*)hu_s)[tid] = ((const float4*)(hidden + (size_t)i0 * 32))[tid];
    __syncthreads();
    for (int idx = tid; idx < 2560; idx += 256){
      int c = idx >> 9; int rem = idx & 511; int ii = rem >> 5; int e = rem & 31;
      const float* wc = dec_w + (size_t)c * 1024 + e;
      const float* hr = hu_s + ii * 32;
      float s = 0.f;
#pragma unroll
      for (int d = 0; d < 32; d++) s += hr[d] * wc[d * 32];
      tsf[(c * 16 + ii) * 36 + e] = s;
    }
    __syncthreads();
    int m = lane & 15, q = lane >> 4;
    short8v a_hi[5], a_lo[5];
#pragma unroll
    for (int c = 0; c < 5; c++){
      const float* p = &tsf[(c * 16 + m) * 36 + q * 8];
      float4 f0 = *(const float4*)p;
      float4 f1 = *(const float4*)(p + 4);
      float fa[8] = {f0.x, f0.y, f0.z, f0.w, f1.x, f1.y, f1.z, f1.w};
      short8v hi, lo;
#pragma unroll
      for (int e = 0; e < 8; e++){
        u16 h = f2bf(fa[e]);
        hi[e] = (short)h;
        lo[e] = (short)f2bf(fa[e] - bf2f(h));
      }
      a_hi[c] = hi; a_lo[c] = lo;
    }
    const float* hv = hidden + 2048 * 32;
    float lsum = 0.f; int acnt = 0;
    int jw0 = blockIdx.x * 256 + w * 64;
#pragma unroll
    for (int jj = 0; jj < 4; jj++){
      int j0 = jw0 + jj * 16;
      const float* pb = hv + (size_t)(j0 + m) * 32 + q * 8;
      float4 g0 = *(const float4*)pb;
      float4 g1 = *(const float4*)(pb + 4);
      float fb[8] = {g0.x, g0.y, g0.z, g0.w, g1.x, g1.y, g1.z, g1.w};
      short8v b_hi, b_lo;
#pragma unroll
      for (int e = 0; e < 8; e++){
        u16 h = f2bf(fb[e]);
        b_hi[e] = (short)h;
        b_lo[e] = (short)f2bf(fb[e] - bf2f(h));
      }
      f32x4 acc[5];
      f32x4 z4 = {0.f, 0.f, 0.f, 0.f};
#pragma unroll
      for (int c = 0; c < 5; c++){
        f32x4 a = __builtin_amdgcn_mfma_f32_16x16x32_bf16(a_hi[c], b_hi, z4, 0, 0, 0);
        a = __builtin_amdgcn_mfma_f32_16x16x32_bf16(a_hi[c], b_lo, a, 0, 0, 0);
        a = __builtin_amdgcn_mfma_f32_16x16x32_bf16(a_lo[c], b_hi, a, 0, 0, 0);
        acc[c] = a;
      }
      int jcol = j0 + m;
#pragma unroll
      for (int r = 0; r < 4; r++){
        int irow = i0 + q * 4 + r;
        float l5[5] = {acc[0][r], acc[1][r], acc[2][r], acc[3][r], acc[4][r]};
        int lab = L[(size_t)irow * 2048 + jcol];
        EPI(l5, lab, mhat + (size_t)irow * 2048 + jcol);
      }
    }
#pragma unroll
    for (int o = 32; o > 0; o >>= 1){ lsum += __shfl_down(lsum, o); acnt += __shfl_down(acnt, o); }
    if (lane == 0){ wl[w] = lsum; wa[w] = acnt; }
    __syncthreads();
    if (tid == 0){
      int pb = blockIdx.y * 8 + blockIdx.x;
      lpart[pb] = wl[0] + wl[1] + wl[2] + wl[3];
      apart[pb] = wa[0] + wa[1] + wa[2] + wa[3];
    }
    __syncthreads();
  }
}

// ---------------------------------------------------------------------------
// K6: final reduce (unchanged, REP=1)
// ---------------------------------------------------------------------------
__global__ __launch_bounds__(256) void k_final(const float* __restrict__ lpart, const int* __restrict__ apart,
                                               const int* __restrict__ di, float* __restrict__ out){
  __shared__ float lred[256];
  __shared__ int ared[256], nred[256];
  int tid = threadIdx.x;
  float ls = 0.f; int as = 0;
#pragma unroll
  for (int k = 0; k < 4; k++){ ls += lpart[tid + k * 256]; as += apart[tid + k * 256]; }
  int ns = 0;
#pragma unroll
  for (int k = 0; k < 8; k++) ns += di[tid + k * 256];
  lred[tid] = ls; ared[tid] = as; nred[tid] = ns;
  __syncthreads();
  for (int s = 128; s > 0; s >>= 1){
    if (tid < s){ lred[tid] += lred[tid + s]; ared[tid] += ared[tid + s]; nred[tid] += nred[tid + s]; }
    __syncthreads();
  }
  if (tid == 0){
    float n = fmaxf((float)nred[0], 1.0f);
    out[0] = lred[0] / n;
    out[1] = ((float)ared[0]) / n;
  }
}

extern "C" void kernel_launch(void* const* d_in, const int* in_sizes, int n_in,
                              void* d_out, int out_size, void* d_ws, size_t ws_size,
                              hipStream_t stream){
  const int*   u       = (const int*)d_in[0];
  const int*   v       = (const int*)d_in[1];
  const float* ratings = (const float*)d_in[2];
  const float* u_emb   = (const float*)d_in[3];
  const float* v_emb   = (const float*)d_in[4];
  const float* gc_w    = (const float*)d_in[5];
  const float* gc_b    = (const float*)d_in[6];
  const float* dense_w = (const float*)d_in[7];
  const float* dense_b = (const float*)d_in[8];
  const float* dec_w   = (const float*)d_in[9];
  float* out = (float*)d_out;
  char* ws = (char*)d_ws;

  u8*    L       = (u8*)(ws + 0);                 // 4 MB
  u8*    LT      = (u8*)(ws + 4194304);           // 4 MB
  float* S       = (float*)(ws + 8388608);        // 5 MB: [5][4096][64]
  float* aggsum  = (float*)(ws + 13631488);       // 1 MB: [4096][64]
  float* hidden  = (float*)(ws + 14680064);       // 512 KB: [4096][32]
  int*   du      = (int*)(ws + 15204352);         // 8 KB
  int*   di      = (int*)(ws + 15212544);         // 8 KB
  float* lpart   = (float*)(ws + 15220736);       // 4 KB: [1024]
  int*   apart   = (int*)(ws + 15224832);         // 4 KB: [1024]

  k_labels <<<2048, 256, 0, stream>>>(u, v, ratings, L, di);
  k_trsup  <<<1344, 256, 0, stream>>>(L, LT, u, v, u_emb, v_emb, gc_w, S);
  k_agg    <<<4096, 256, 0, stream>>>(L, LT, S, aggsum, du);
  k_hidden <<<1024, 256, 0, stream>>>(aggsum, du, di, gc_b, dense_w, dense_b, hidden);
  k_logits <<<dim3(8, 128), 256, 0, stream>>>(hidden, dec_w, L, out, lpart, apart);
  k_final  <<<1, 256, 0, stream>>>(lpart, apart, di, out + 4194304);
}

// Round 12
// 94.032 us; speedup vs baseline: 23.0336x; 23.0336x over previous
//
#include <hip/hip_runtime.h>
#include <hip/hip_bf16.h>
#include <cstdint>

#define RST 16777216  // 4096*4096 floats per rating class
typedef unsigned short u16;
typedef unsigned char u8;
typedef __attribute__((ext_vector_type(8))) short short8v;   // 8 bf16 in 4 VGPRs
typedef __attribute__((ext_vector_type(4))) float f32x4;

__device__ __forceinline__ u16 f2bf(float x){
  unsigned int b = __float_as_uint(x);
  unsigned int r = (b + 0x7FFFu + ((b >> 16) & 1u)) >> 16;
  return (u16)r;
}
__device__ __forceinline__ float bf2f(u16 h){
  return __uint_as_float(((unsigned int)h) << 16);
}
__device__ __forceinline__ void split8(const float* fa, short8v& hi, short8v& lo){
#pragma unroll
  for (int e = 0; e < 8; e++){
    u16 h = f2bf(fa[e]);
    hi[e] = (short)h;
    lo[e] = (short)f2bf(fa[e] - bf2f(h));
  }
}

// ---------------------------------------------------------------------------
// K1: label extraction + di row-counts. One block per batch-row i. (r3 form)
// ---------------------------------------------------------------------------
__global__ __launch_bounds__(256) void k_labels(const int* __restrict__ u, const int* __restrict__ v,
                                                const float* __restrict__ ratings, u8* __restrict__ L,
                                                int* __restrict__ di){
  __shared__ float row[4096];
  __shared__ int wsum[4];
  int i = blockIdx.x;
  int tid = threadIdx.x;
  int lane = tid & 63, wid = tid >> 6;
  int U = u[i];
  int j0 = tid * 8;
  int vj[8];
#pragma unroll
  for (int k = 0; k < 8; k++) vj[k] = v[j0 + k];
  int lab[8];
#pragma unroll
  for (int k = 0; k < 8; k++) lab[k] = 5;
  const float* rbase = ratings + (size_t)U * 4096;
  for (int c = 0; c < 5; c++){
    const float4* src = (const float4*)(rbase + (size_t)c * RST);
#pragma unroll
    for (int k = 0; k < 4; k++) ((float4*)row)[tid + k*256] = src[tid + k*256];
    __syncthreads();
#pragma unroll
    for (int k = 0; k < 8; k++) if (row[vj[k]] > 0.5f) lab[k] = c;
    __syncthreads();
  }
  unsigned int lo = 0, hi = 0;
  int cnt = 0;
#pragma unroll
  for (int k = 0; k < 4; k++){
    lo |= ((unsigned)lab[k]) << (8*k); hi |= ((unsigned)lab[k+4]) << (8*k);
    cnt += (lab[k] != 5); cnt += (lab[k+4] != 5);
  }
  *(uint2*)(L + (size_t)i * 2048 + j0) = make_uint2(lo, hi);
#pragma unroll
  for (int o = 32; o > 0; o >>= 1) cnt += __shfl_down(cnt, o);
  if (lane == 0) wsum[wid] = cnt;
  __syncthreads();
  if (tid == 0) di[i] = wsum[0] + wsum[1] + wsum[2] + wsum[3];
}

// ---------------------------------------------------------------------------
// K2: fused [byte transpose L->LT] + [support S = x . gc_w via split-bf16 MFMA].
// blocks 0..1023: transpose. blocks 1024..1343: support (c = b>>6, nblk = b&63).
// Support: wave wv owns h-tile [wv*16, wv*16+16); B-frag = gc_w^T rows (strided
// gather, loaded once); 4 row-tiles of 16 x-rows gathered from global; per tile
// 2 K-chunks x 3 MFMAs (hi.hi + hi.lo + lo.hi). C: col=lane&15, row=(lane>>4)*4+reg.
// ---------------------------------------------------------------------------
__global__ __launch_bounds__(256) void k_trsup(const u8* __restrict__ L, u8* __restrict__ LT,
    const int* __restrict__ u, const int* __restrict__ v,
    const float* __restrict__ u_emb, const float* __restrict__ v_emb, const float* __restrict__ gc_w,
    float* __restrict__ S){
  __shared__ u8 tile[64][64];
  int tid = threadIdx.x;
  if (blockIdx.x < 1024){
    int jb = blockIdx.x & 31, ib = blockIdx.x >> 5;
    int i0 = ib * 64, j0 = jb * 64;
    int r = tid >> 2, cq = tid & 3;
    uint4 d = *(const uint4*)(L + (size_t)(i0 + r) * 2048 + j0 + cq * 16);
    *(uint4*)&tile[r][cq * 16] = d;
    __syncthreads();
    u8 ob[16];
#pragma unroll
    for (int k = 0; k < 16; k++) ob[k] = tile[cq * 16 + k][r];
    *(uint4*)(LT + (size_t)(j0 + r) * 2048 + i0 + cq * 16) = *(uint4*)ob;
  } else {
    int b = blockIdx.x - 1024;
    int c = b >> 6, nblk = b & 63;
    int lane = tid & 63, wv = tid >> 6;
    int m = lane & 15, q = lane >> 4;
    int n0 = nblk * 64;
    bool uside = (n0 < 2048);
    const int* nidx = uside ? u : v;
    const float* emb = uside ? u_emb : v_emb;
    int nbase = uside ? n0 : (n0 - 2048);
    int h0 = wv * 16;
    // B-frags: brow_{h0+m}[k] = gc_w[c][k][h0+m], k = ch*32 + q*8 + e
    short8v bh[2], bl[2];
#pragma unroll
    for (int ch = 0; ch < 2; ch++){
      const float* wp = gc_w + c * 4096 + (ch * 32 + q * 8) * 64 + h0 + m;
      float fb[8];
#pragma unroll
      for (int e = 0; e < 8; e++) fb[e] = wp[e * 64];
      split8(fb, bh[ch], bl[ch]);
    }
#pragma unroll
    for (int rt = 0; rt < 4; rt++){
      const float* xr = emb + (size_t)nidx[nbase + rt * 16 + m] * 64;
      f32x4 acc = {0.f, 0.f, 0.f, 0.f};
#pragma unroll
      for (int ch = 0; ch < 2; ch++){
        float fa[8];
        *(float4*)&fa[0] = *(const float4*)(xr + ch * 32 + q * 8);
        *(float4*)&fa[4] = *(const float4*)(xr + ch * 32 + q * 8 + 4);
        short8v ah, al;
        split8(fa, ah, al);
        acc = __builtin_amdgcn_mfma_f32_16x16x32_bf16(ah, bh[ch], acc, 0, 0, 0);
        acc = __builtin_amdgcn_mfma_f32_16x16x32_bf16(ah, bl[ch], acc, 0, 0, 0);
        acc = __builtin_amdgcn_mfma_f32_16x16x32_bf16(al, bh[ch], acc, 0, 0, 0);
      }
      int h = h0 + m;
      int rbase = n0 + rt * 16 + q * 4;
#pragma unroll
      for (int reg = 0; reg < 4; reg++)
        S[((size_t)c * 4096 + rbase + reg) * 64 + h] = acc[reg];
    }
  }
}

// ---------------------------------------------------------------------------
// K3: sparse aggregate, in-block compaction (r7 form).
// ---------------------------------------------------------------------------
__global__ __launch_bounds__(256) void k_agg(const u8* __restrict__ L, const u8* __restrict__ LT,
    const float* __restrict__ S, float* __restrict__ aggsum, int* __restrict__ du){
  __shared__ u16 lst[2048];
  __shared__ int wbase[4];
  __shared__ float red[4][64];
  int r = blockIdx.x;
  int tid = threadIdx.x;
  int lane = tid & 63, wid = tid >> 6;
  bool uside = (r < 2048);
  const u8* rowp = uside ? (L + (size_t)r * 2048) : (LT + (size_t)(r - 2048) * 2048);
  uint2 d = ((const uint2*)rowp)[tid];
  int lab[8];
#pragma unroll
  for (int k = 0; k < 4; k++){ lab[k] = (d.x >> (8*k)) & 255; lab[k+4] = (d.y >> (8*k)) & 255; }
  int cnt = 0;
#pragma unroll
  for (int k = 0; k < 8; k++) cnt += (lab[k] != 5);
  int pre = cnt;
#pragma unroll
  for (int o = 1; o < 64; o <<= 1){ int t = __shfl_up(pre, o); if (lane >= o) pre += t; }
  if (lane == 63) wbase[wid] = pre;
  __syncthreads();
  int base = 0;
#pragma unroll
  for (int w = 0; w < 4; w++) base += (w < wid) ? wbase[w] : 0;
  int total = wbase[0] + wbase[1] + wbase[2] + wbase[3];
  int off = base + (pre - cnt);
  int j0 = tid * 8;
#pragma unroll
  for (int k = 0; k < 8; k++)
    if (lab[k] != 5) lst[off++] = (u16)(((j0 + k) << 3) | lab[k]);
  if (!uside && tid == 0) du[r - 2048] = total;
  __syncthreads();
  const float* Sop = S + (uside ? 131072 : 0) + lane;
  int e0 = (wid * total) >> 2, e1 = ((wid + 1) * total) >> 2;
  float a0 = 0.f, a1 = 0.f, a2 = 0.f, a3 = 0.f;
  int e = e0;
  for (; e + 4 <= e1; e += 4){
    int x0 = lst[e], x1 = lst[e+1], x2 = lst[e+2], x3 = lst[e+3];
    a0 += Sop[(size_t)(x0 & 7) * 262144 + (size_t)(x0 >> 3) * 64];
    a1 += Sop[(size_t)(x1 & 7) * 262144 + (size_t)(x1 >> 3) * 64];
    a2 += Sop[(size_t)(x2 & 7) * 262144 + (size_t)(x2 >> 3) * 64];
    a3 += Sop[(size_t)(x3 & 7) * 262144 + (size_t)(x3 >> 3) * 64];
  }
  for (; e < e1; e++){
    int x = lst[e];
    a0 += Sop[(size_t)(x & 7) * 262144 + (size_t)(x >> 3) * 64];
  }
  red[wid][lane] = (a0 + a1) + (a2 + a3);
  __syncthreads();
  if (wid == 0) aggsum[(size_t)r * 64 + lane] = red[0][lane] + red[1][lane] + red[2][lane] + red[3][lane];
}

// ---------------------------------------------------------------------------
// K4: hidden = sigmoid(relu(inv*agg + b) @ dense_w + dense_b)  (r7 form)
// ---------------------------------------------------------------------------
__global__ __launch_bounds__(256) void k_hidden(const float* __restrict__ aggsum, const int* __restrict__ du, const int* __restrict__ di,
    const float* __restrict__ gc_b, const float* __restrict__ dense_w, const float* __restrict__ dense_b,
    float* __restrict__ hidden){
  int wid = threadIdx.x >> 6, lane = threadIdx.x & 63;
  int r = blockIdx.x * 4 + wid;
  float a = aggsum[(size_t)r * 64 + lane];
  int cnt = (r < 2048) ? du[r] : di[r - 2048];
  float inv = (cnt > 0) ? (1.0f / (float)cnt) : 0.0f;
  float bsum = 0.f;
#pragma unroll
  for (int c = 0; c < 5; c++) bsum += gc_b[c * 64 + lane];
  float z = fmaxf(a * inv + bsum, 0.f);
  __shared__ float zb[4][64];
  zb[wid][lane] = z;
  __syncthreads();
  if (lane < 32){
    float s = dense_b[lane];
#pragma unroll
    for (int h = 0; h < 64; h++) s += zb[wid][h] * dense_w[h * 32 + lane];
    hidden[(size_t)r * 32 + lane] = 1.0f / (1.0f + __expf(-s));
  }
}

// ---------------------------------------------------------------------------
// K5: MFMA logits (r7 form).
// ---------------------------------------------------------------------------
#define EPI(l, lab, outp) do{ \
  float mx = fmaxf(fmaxf(fmaxf(l[0], l[1]), fmaxf(l[2], l[3])), l[4]); \
  float e0 = __expf(l[0]-mx), e1 = __expf(l[1]-mx), e2 = __expf(l[2]-mx), e3 = __expf(l[3]-mx), e4 = __expf(l[4]-mx); \
  float ssum = e0 + e1 + e2 + e3 + e4; \
  *(outp) = (e1 + 2.f*e2 + 3.f*e3 + 4.f*e4) / ssum; \
  if ((lab) < 5){ \
    int pred = 0; float bm = l[0]; \
    if (l[1] > bm){ bm = l[1]; pred = 1; } \
    if (l[2] > bm){ bm = l[2]; pred = 2; } \
    if (l[3] > bm){ bm = l[3]; pred = 3; } \
    if (l[4] > bm){ bm = l[4]; pred = 4; } \
    float ll = (lab)==0 ? l[0] : ((lab)==1 ? l[1] : ((lab)==2 ? l[2] : ((lab)==3 ? l[3] : l[4]))); \
    lsum += __logf(ssum) + mx - ll; \
    acnt += (pred == (lab)); \
  } \
}while(0)

__global__ __launch_bounds__(256) void k_logits(const float* __restrict__ hidden, const float* __restrict__ dec_w,
    const u8* __restrict__ L, float* __restrict__ mhat, float* __restrict__ lpart, int* __restrict__ apart){
  __shared__ float hu_s[512];          // 16 x 32
  __shared__ float tsf[5 * 16 * 36];   // padded stride 36
  int tid = threadIdx.x;
  int lane = tid & 63, w = tid >> 6;
  int i0 = blockIdx.y * 16;
  if (tid < 128) ((float4*)hu_s)[tid] = ((const float4*)(hidden + (size_t)i0 * 32))[tid];
  __syncthreads();
  for (int idx = tid; idx < 2560; idx += 256){
    int c = idx >> 9; int rem = idx & 511; int ii = rem >> 5; int e = rem & 31;
    const float* wc = dec_w + (size_t)c * 1024 + e;
    const float* hr = hu_s + ii * 32;
    float s = 0.f;
#pragma unroll
    for (int d = 0; d < 32; d++) s += hr[d] * wc[d * 32];
    tsf[(c * 16 + ii) * 36 + e] = s;
  }
  __syncthreads();
  int m = lane & 15, q = lane >> 4;
  short8v a_hi[5], a_lo[5];
#pragma unroll
  for (int c = 0; c < 5; c++){
    const float* p = &tsf[(c * 16 + m) * 36 + q * 8];
    float fa[8];
    *(float4*)&fa[0] = *(const float4*)p;
    *(float4*)&fa[4] = *(const float4*)(p + 4);
    split8(fa, a_hi[c], a_lo[c]);
  }
  const float* hv = hidden + 2048 * 32;
  float lsum = 0.f; int acnt = 0;
  int jw0 = blockIdx.x * 256 + w * 64;
#pragma unroll
  for (int jj = 0; jj < 4; jj++){
    int j0 = jw0 + jj * 16;
    const float* pb = hv + (size_t)(j0 + m) * 32 + q * 8;
    float fb[8];
    *(float4*)&fb[0] = *(const float4*)pb;
    *(float4*)&fb[4] = *(const float4*)(pb + 4);
    short8v b_hi, b_lo;
    split8(fb, b_hi, b_lo);
    f32x4 acc[5];
    f32x4 z4 = {0.f, 0.f, 0.f, 0.f};
#pragma unroll
    for (int c = 0; c < 5; c++){
      f32x4 a = __builtin_amdgcn_mfma_f32_16x16x32_bf16(a_hi[c], b_hi, z4, 0, 0, 0);
      a = __builtin_amdgcn_mfma_f32_16x16x32_bf16(a_hi[c], b_lo, a, 0, 0, 0);
      a = __builtin_amdgcn_mfma_f32_16x16x32_bf16(a_lo[c], b_hi, a, 0, 0, 0);
      acc[c] = a;
    }
    int jcol = j0 + m;
#pragma unroll
    for (int r = 0; r < 4; r++){
      int irow = i0 + q * 4 + r;
      float l5[5] = {acc[0][r], acc[1][r], acc[2][r], acc[3][r], acc[4][r]};
      int lab = L[(size_t)irow * 2048 + jcol];
      EPI(l5, lab, mhat + (size_t)irow * 2048 + jcol);
    }
  }
#pragma unroll
  for (int o = 32; o > 0; o >>= 1){ lsum += __shfl_down(lsum, o); acnt += __shfl_down(acnt, o); }
  __shared__ float wl[4]; __shared__ int wa[4];
  if (lane == 0){ wl[w] = lsum; wa[w] = acnt; }
  __syncthreads();
  if (tid == 0){
    int pb = blockIdx.y * 8 + blockIdx.x;
    lpart[pb] = wl[0] + wl[1] + wl[2] + wl[3];
    apart[pb] = wa[0] + wa[1] + wa[2] + wa[3];
  }
}

// ---------------------------------------------------------------------------
// K6: final reduce over 1024 partials + n_obs = sum(di)
// ---------------------------------------------------------------------------
__global__ __launch_bounds__(256) void k_final(const float* __restrict__ lpart, const int* __restrict__ apart,
                                               const int* __restrict__ di, float* __restrict__ out){
  __shared__ float lred[256];
  __shared__ int ared[256], nred[256];
  int tid = threadIdx.x;
  float ls = 0.f; int as = 0;
#pragma unroll
  for (int k = 0; k < 4; k++){ ls += lpart[tid + k * 256]; as += apart[tid + k * 256]; }
  int ns = 0;
#pragma unroll
  for (int k = 0; k < 8; k++) ns += di[tid + k * 256];
  lred[tid] = ls; ared[tid] = as; nred[tid] = ns;
  __syncthreads();
  for (int s = 128; s > 0; s >>= 1){
    if (tid < s){ lred[tid] += lred[tid + s]; ared[tid] += ared[tid + s]; nred[tid] += nred[tid + s]; }
    __syncthreads();
  }
  if (tid == 0){
    float n = fmaxf((float)nred[0], 1.0f);
    out[0] = lred[0] / n;
    out[1] = ((float)ared[0]) / n;
  }
}

extern "C" void kernel_launch(void* const* d_in, const int* in_sizes, int n_in,
                              void* d_out, int out_size, void* d_ws, size_t ws_size,
                              hipStream_t stream){
  const int*   u       = (const int*)d_in[0];
  const int*   v       = (const int*)d_in[1];
  const float* ratings = (const float*)d_in[2];
  const float* u_emb   = (const float*)d_in[3];
  const float* v_emb   = (const float*)d_in[4];
  const float* gc_w    = (const float*)d_in[5];
  const float* gc_b    = (const float*)d_in[6];
  const float* dense_w = (const float*)d_in[7];
  const float* dense_b = (const float*)d_in[8];
  const float* dec_w   = (const float*)d_in[9];
  float* out = (float*)d_out;
  char* ws = (char*)d_ws;

  u8*    L       = (u8*)(ws + 0);                 // 4 MB
  u8*    LT      = (u8*)(ws + 4194304);           // 4 MB
  float* S       = (float*)(ws + 8388608);        // 5 MB: [5][4096][64]
  float* aggsum  = (float*)(ws + 13631488);       // 1 MB: [4096][64]
  float* hidden  = (float*)(ws + 14680064);       // 512 KB: [4096][32]
  int*   du      = (int*)(ws + 15204352);         // 8 KB
  int*   di      = (int*)(ws + 15212544);         // 8 KB
  float* lpart   = (float*)(ws + 15220736);       // 4 KB: [1024]
  int*   apart   = (int*)(ws + 15224832);         // 4 KB: [1024]

  k_labels <<<2048, 256, 0, stream>>>(u, v, ratings, L, di);
  k_trsup  <<<1344, 256, 0, stream>>>(L, LT, u, v, u_emb, v_emb, gc_w, S);
  k_agg    <<<4096, 256, 0, stream>>>(L, LT, S, aggsum, du);
  k_hidden <<<1024, 256, 0, stream>>>(aggsum, du, di, gc_b, dense_w, dense_b, hidden);
  k_logits <<<dim3(8, 128), 256, 0, stream>>>(hidden, dec_w, L, out, lpart, apart);
  k_final  <<<1, 256, 0, stream>>>(lpart, apart, di, out + 4194304);
}